// Round 2
// baseline (268.566 us; speedup 1.0000x reference)
//
#include <hip/hip_runtime.h>

// Soft-DTW gradient, batch=64, 256x256, gamma=0.01 — forward/backward-DP form.
// R16 = R15 (F/B independent suffix-DP, 183us kernel) with the DP converted
// from 2 waves/128 lanes/R=2 to ONE wave per block: 64 lanes, R=4 rows/lane,
// 4-col groups, skew m = g + L (L=0..63). The neighbor exchange (lane L-1's
// bottom row -> lane L) is now 4x __shfl_up + cndmask: NO LDS, NO s_barrier,
// NO lgkmcnt(0) drain anywhere in the DP. Pipeline also shortens: 129 bodies
// (m=-2..126) instead of 195. R15's per-body cost was ~2250 cy of which ~80%
// was the 2-wave barrier rendezvous + LDS exchange; this removes it entirely.
// E(i,j) = exp2( K2*theta(i,j) + F'tot - F'(i,j) - B'(i,j) ), scaled domain
// V' = V/(gamma*ln2). 128 blocks x 64 threads: blocks 0..63 = F of element b,
// 64..127 = B (index-reversed DP, stored mirrored). Device-scope flag barrier,
// then fused epilogue + batch mean (block -> 2 output rows).
// ws: F planes [64][65536] f32, B planes [64][65536] f32, counter u32.

#define MM 256
#define NN 256
#define R 4              // rows per lane
#define NB 64            // batch elements
#define NBLK 128         // DP blocks: 64 forward + 64 backward
#define SBIG 1.0e12f     // "infinity" in the scaled domain
#define K2   144.269504089f     // 1/(gamma*ln2) = (1/gamma)*log2(e)

__device__ __forceinline__ float f4get(const float4& v, int k) {
    switch (k) { case 0: return v.x; case 1: return v.y; case 2: return v.z; default: return v.w; }
}
__device__ __forceinline__ int iclamp(int x, int lo, int hi) {
    return x < lo ? lo : (x > hi ? hi : x);
}

// One soft-DTW value DP (forward recurrence) over the virtual matrix.
// REV=false: virtual == physical (computes F').
// REV=true : virtual (i,j) = physical (255-i, 255-j)  (computes B', stored
//            mirrored so Vp[i][j] = B'(i,j) in physical coordinates).
// Single wave: lane L owns virtual rows 4L..4L+3; group g = m - L covers
// virtual cols 4g..4g+3.
template<bool REV>
__device__ __forceinline__ void run_dp(const float* __restrict__ th,
                                       float* __restrict__ Vp)
{
    const int L = threadIdx.x;                      // 0..63

    float vprev[R];
    #pragma unroll
    for (int r = 0; r < R; ++r) vprev[r] = SBIG;
    float4 rec = make_float4(SBIG, SBIG, SBIG, SBIG);   // row above, cols 4g..4g+3
    float prevW = SBIG;                                  // row above, col 4g-1
    float4 botV4 = make_float4(SBIG, SBIG, SBIG, SBIG);  // own bottom row this body
    float4 thB[3][R];
    #pragma unroll
    for (int p = 0; p < 3; ++p)
        #pragma unroll
        for (int r = 0; r < R; ++r) thB[p][r] = make_float4(0.f, 0.f, 0.f, 0.f);

    auto body = [&](const int LD, const int CU, const int m) {
        const int g = m - L;
        const int gl = iclamp(g + 2, 0, 63);        // prefetch distance 2
        #pragma unroll
        for (int r = 0; r < R; ++r) {
            const int vr = 4 * L + r;               // virtual row
            if (REV) {
                const float4 t = *(const float4*)(th + (255 - vr) * NN + (252 - 4 * gl));
                thB[LD][r] = make_float4(t.w, t.z, t.y, t.x);   // reverse cols
            } else {
                thB[LD][r] = *(const float4*)(th + vr * NN + 4 * gl);
            }
        }
        if ((unsigned)g <= 63u) {
            const float4 topV = rec;                // row above, cols 4g..4g+3
            const float vd0 = (g == 0) ? ((L == 0) ? 0.0f : SBIG) : prevW;
            float vbuf[R][4];
            #pragma unroll
            for (int cc = 0; cc < 4; ++cc) {
                float vu = f4get(topV, cc);
                float vd = (cc == 0) ? vd0 : f4get(topV, cc - 1);
                #pragma unroll
                for (int r = 0; r < R; ++r) {
                    const float vl = vprev[r];
                    const float mn = fminf(vl, fminf(vd, vu));
                    const float el = exp2f(mn - vl);
                    const float ed = exp2f(mn - vd);
                    const float eu = exp2f(mn - vu);
                    const float ss = el + ed + eu;
                    const float a  = mn - log2f(ss);            // scaled softmin
                    const float v  = fmaf(f4get(thB[CU][r], cc), K2, a);
                    vbuf[r][cc] = v;
                    vd = vl;
                    vu = v;
                    vprev[r] = v;
                }
            }
            botV4 = make_float4(vbuf[R - 1][0], vbuf[R - 1][1], vbuf[R - 1][2], vbuf[R - 1][3]);
            #pragma unroll
            for (int r = 0; r < R; ++r) {
                const int vr = 4 * L + r;
                if (REV)
                    *(float4*)(Vp + (255 - vr) * NN + (252 - 4 * g)) =
                        make_float4(vbuf[r][3], vbuf[r][2], vbuf[r][1], vbuf[r][0]);
                else
                    *(float4*)(Vp + vr * NN + 4 * g) =
                        make_float4(vbuf[r][0], vbuf[r][1], vbuf[r][2], vbuf[r][3]);
            }
        }
        // ---- in-wave exchange: lane L receives lane L-1's bottom row ----
        float4 nr;
        nr.x = __shfl_up(botV4.x, 1);
        nr.y = __shfl_up(botV4.y, 1);
        nr.z = __shfl_up(botV4.z, 1);
        nr.w = __shfl_up(botV4.w, 1);
        prevW = rec.w;
        if (L == 0) nr = make_float4(SBIG, SBIG, SBIG, SBIG);   // boundary row
        rec = nr;
    };
    for (int k = 0; k < 129; k += 3) {              // m = -2 .. 126
        body(0, 1, k - 2);
        body(1, 2, k - 1);
        body(2, 0, k);
    }
}

__global__ __launch_bounds__(64) void dtw_fb(
    const float* __restrict__ D,
    float* __restrict__ out,          // [256][256]
    float* __restrict__ ws)
{
    const int blk = blockIdx.x;
    const bool rev = blk >= NB;
    const int b = rev ? blk - NB : blk;
    const float* __restrict__ th = D + (size_t)b * (MM * NN);
    float* __restrict__ Fp = ws + (size_t)b * (MM * NN);
    float* __restrict__ Bp = ws + (size_t)(NB + b) * (MM * NN);
    unsigned* ctr = (unsigned*)(ws + (size_t)2 * NB * (MM * NN));

    if (rev) run_dp<true >(th, Bp);
    else     run_dp<false>(th, Fp);

    // ---------------- device-scope barrier (128 blocks, 1 wave each) ----------------
    __threadfence();                   // release V-plane stores (L2 writeback)
    if (threadIdx.x == 0)
        __hip_atomic_fetch_add(ctr, 1u, __ATOMIC_ACQ_REL, __HIP_MEMORY_SCOPE_AGENT);
    unsigned cnt;
    do {
        cnt = __hip_atomic_load(ctr, __ATOMIC_ACQUIRE, __HIP_MEMORY_SCOPE_AGENT);
        if (cnt < NBLK) __builtin_amdgcn_s_sleep(2);
    } while (cnt < NBLK);
    __builtin_amdgcn_fence(__ATOMIC_ACQUIRE, "agent");   // invalidate caches

    // ---------------- fused epilogue + batch mean ----------------
    // E_b(i,j) = exp2( K2*theta + F'tot_b - F'_b(i,j) - B'_b(i,j) );
    // block blk owns output rows 2*blk, 2*blk+1; thread t: row 2*blk+(t>>5),
    // cols 4*(t&31) and 4*(t&31)+128.
    {
        const int t = threadIdx.x;
        const int row = 2 * blk + (t >> 5);
        const int cb  = 4 * (t & 31);
        const size_t off0 = (size_t)row * NN + cb;
        const size_t off1 = off0 + 128;
        float4 acc0 = make_float4(0.f, 0.f, 0.f, 0.f);
        float4 acc1 = make_float4(0.f, 0.f, 0.f, 0.f);
        for (int p = 0; p < NB; ++p) {
            const float* __restrict__ thp = D + (size_t)p * (MM * NN);
            const float* __restrict__ fp  = ws + (size_t)p * (MM * NN);
            const float* __restrict__ bp  = ws + (size_t)(NB + p) * (MM * NN);
            const float Ft = fp[MM * NN - 1];                 // F'tot = F'(M,N)
            const float4 t0 = *(const float4*)(thp + off0);
            const float4 f0 = *(const float4*)(fp + off0);
            const float4 b0 = *(const float4*)(bp + off0);
            acc0.x += exp2f(fmaf(t0.x, K2, (Ft - f0.x) - b0.x));
            acc0.y += exp2f(fmaf(t0.y, K2, (Ft - f0.y) - b0.y));
            acc0.z += exp2f(fmaf(t0.z, K2, (Ft - f0.z) - b0.z));
            acc0.w += exp2f(fmaf(t0.w, K2, (Ft - f0.w) - b0.w));
            const float4 t1 = *(const float4*)(thp + off1);
            const float4 f1 = *(const float4*)(fp + off1);
            const float4 b1 = *(const float4*)(bp + off1);
            acc1.x += exp2f(fmaf(t1.x, K2, (Ft - f1.x) - b1.x));
            acc1.y += exp2f(fmaf(t1.y, K2, (Ft - f1.y) - b1.y));
            acc1.z += exp2f(fmaf(t1.z, K2, (Ft - f1.z) - b1.z));
            acc1.w += exp2f(fmaf(t1.w, K2, (Ft - f1.w) - b1.w));
        }
        const float inv = 1.0f / (float)NB;
        *(float4*)(out + off0) =
            make_float4(acc0.x * inv, acc0.y * inv, acc0.z * inv, acc0.w * inv);
        *(float4*)(out + off1) =
            make_float4(acc1.x * inv, acc1.y * inv, acc1.z * inv, acc1.w * inv);
    }
}

extern "C" void kernel_launch(void* const* d_in, const int* in_sizes, int n_in,
                              void* d_out, int out_size, void* d_ws, size_t ws_size,
                              hipStream_t stream) {
    const float* D = (const float*)d_in[0];
    float* out = (float*)d_out;
    float* ws = (float*)d_ws;

    // zero the barrier counter (ws is re-poisoned 0xAA before every launch)
    hipMemsetAsync(ws + (size_t)2 * NB * (MM * NN), 0, sizeof(unsigned), stream);
    dtw_fb<<<dim3(NBLK), dim3(64), 0, stream>>>(D, out, ws);
}

// Round 3
// 266.301 us; speedup vs baseline: 1.0085x; 1.0085x over previous
//
#include <hip/hip_runtime.h>

// Soft-DTW gradient, batch=64, 256x256, gamma=0.01 — forward/backward-DP form.
// R17 = R16 + __launch_bounds__(64, 1).
// R16 regressed (231us vs R15's 183us) but exposed the real bottleneck:
// VGPR_Count=48 — the compiler's occupancy heuristic capped registers below
// what the 3-buffer theta prefetch needs (thB alone = 48 VGPRs), so the
// global_load_dwordx4 prefetch was de-pipelined (loads sunk to their uses),
// exposing full load latency every body (~3700 of 4300 cy/body was stall;
// per-cell cost ~270cy constant across R15/R16 structures = memory latency,
// not the softmin chain). With min-waves=1 per EU the allocator may use up
// to 512 VGPRs; the 3-body rotation becomes a real 2-body-deep pipeline
// (~2 body-times of load lead ≈ full HBM latency covered), leaving only the
// true chain (~16 cells x ~60-70cy ≈ 1k cy/body).
// Structure otherwise identical to R16: one wave per block, 64 lanes,
// R=4 rows/lane, 4-col groups, skew m=g+L, shuffle-only neighbor exchange
// (no LDS, no barriers in the DP). 128 blocks: 0..63 = F DP, 64..127 = B DP
// (index-reversed, stored mirrored). E = exp2(K2*theta + F'tot - F' - B'),
// device-scope flag barrier, fused epilogue + batch mean.
// ws: F planes [64][65536] f32, B planes [64][65536] f32, counter u32.

#define MM 256
#define NN 256
#define R 4              // rows per lane
#define NB 64            // batch elements
#define NBLK 128         // DP blocks: 64 forward + 64 backward
#define SBIG 1.0e12f     // "infinity" in the scaled domain
#define K2   144.269504089f     // 1/(gamma*ln2) = (1/gamma)*log2(e)

__device__ __forceinline__ float f4get(const float4& v, int k) {
    switch (k) { case 0: return v.x; case 1: return v.y; case 2: return v.z; default: return v.w; }
}
__device__ __forceinline__ int iclamp(int x, int lo, int hi) {
    return x < lo ? lo : (x > hi ? hi : x);
}

// One soft-DTW value DP (forward recurrence) over the virtual matrix.
// REV=false: virtual == physical (computes F').
// REV=true : virtual (i,j) = physical (255-i, 255-j)  (computes B', stored
//            mirrored so Vp[i][j] = B'(i,j) in physical coordinates).
// Single wave: lane L owns virtual rows 4L..4L+3; group g = m - L covers
// virtual cols 4g..4g+3.
template<bool REV>
__device__ __forceinline__ void run_dp(const float* __restrict__ th,
                                       float* __restrict__ Vp)
{
    const int L = threadIdx.x;                      // 0..63

    float vprev[R];
    #pragma unroll
    for (int r = 0; r < R; ++r) vprev[r] = SBIG;
    float4 rec = make_float4(SBIG, SBIG, SBIG, SBIG);   // row above, cols 4g..4g+3
    float prevW = SBIG;                                  // row above, col 4g-1
    float4 botV4 = make_float4(SBIG, SBIG, SBIG, SBIG);  // own bottom row this body
    float4 thB[3][R];
    #pragma unroll
    for (int p = 0; p < 3; ++p)
        #pragma unroll
        for (int r = 0; r < R; ++r) thB[p][r] = make_float4(0.f, 0.f, 0.f, 0.f);

    auto body = [&](const int LD, const int CU, const int m) {
        const int g = m - L;
        const int gl = iclamp(g + 2, 0, 63);        // prefetch distance 2
        #pragma unroll
        for (int r = 0; r < R; ++r) {
            const int vr = 4 * L + r;               // virtual row
            if (REV) {
                const float4 t = *(const float4*)(th + (255 - vr) * NN + (252 - 4 * gl));
                thB[LD][r] = make_float4(t.w, t.z, t.y, t.x);   // reverse cols
            } else {
                thB[LD][r] = *(const float4*)(th + vr * NN + 4 * gl);
            }
        }
        if ((unsigned)g <= 63u) {
            const float4 topV = rec;                // row above, cols 4g..4g+3
            const float vd0 = (g == 0) ? ((L == 0) ? 0.0f : SBIG) : prevW;
            float vbuf[R][4];
            #pragma unroll
            for (int cc = 0; cc < 4; ++cc) {
                float vu = f4get(topV, cc);
                float vd = (cc == 0) ? vd0 : f4get(topV, cc - 1);
                #pragma unroll
                for (int r = 0; r < R; ++r) {
                    const float vl = vprev[r];
                    const float mn = fminf(vl, fminf(vd, vu));
                    const float el = exp2f(mn - vl);
                    const float ed = exp2f(mn - vd);
                    const float eu = exp2f(mn - vu);
                    const float ss = el + ed + eu;
                    const float a  = mn - log2f(ss);            // scaled softmin
                    const float v  = fmaf(f4get(thB[CU][r], cc), K2, a);
                    vbuf[r][cc] = v;
                    vd = vl;
                    vu = v;
                    vprev[r] = v;
                }
            }
            botV4 = make_float4(vbuf[R - 1][0], vbuf[R - 1][1], vbuf[R - 1][2], vbuf[R - 1][3]);
            #pragma unroll
            for (int r = 0; r < R; ++r) {
                const int vr = 4 * L + r;
                if (REV)
                    *(float4*)(Vp + (255 - vr) * NN + (252 - 4 * g)) =
                        make_float4(vbuf[r][3], vbuf[r][2], vbuf[r][1], vbuf[r][0]);
                else
                    *(float4*)(Vp + vr * NN + 4 * g) =
                        make_float4(vbuf[r][0], vbuf[r][1], vbuf[r][2], vbuf[r][3]);
            }
        }
        // ---- in-wave exchange: lane L receives lane L-1's bottom row ----
        float4 nr;
        nr.x = __shfl_up(botV4.x, 1);
        nr.y = __shfl_up(botV4.y, 1);
        nr.z = __shfl_up(botV4.z, 1);
        nr.w = __shfl_up(botV4.w, 1);
        prevW = rec.w;
        if (L == 0) nr = make_float4(SBIG, SBIG, SBIG, SBIG);   // boundary row
        rec = nr;
    };
    for (int k = 0; k < 129; k += 3) {              // m = -2 .. 126
        body(0, 1, k - 2);
        body(1, 2, k - 1);
        body(2, 0, k);
    }
}

__global__ __launch_bounds__(64, 1) void dtw_fb(
    const float* __restrict__ D,
    float* __restrict__ out,          // [256][256]
    float* __restrict__ ws)
{
    const int blk = blockIdx.x;
    const bool rev = blk >= NB;
    const int b = rev ? blk - NB : blk;
    const float* __restrict__ th = D + (size_t)b * (MM * NN);
    float* __restrict__ Fp = ws + (size_t)b * (MM * NN);
    float* __restrict__ Bp = ws + (size_t)(NB + b) * (MM * NN);
    unsigned* ctr = (unsigned*)(ws + (size_t)2 * NB * (MM * NN));

    if (rev) run_dp<true >(th, Bp);
    else     run_dp<false>(th, Fp);

    // ---------------- device-scope barrier (128 blocks, 1 wave each) ----------------
    __threadfence();                   // release V-plane stores (L2 writeback)
    if (threadIdx.x == 0)
        __hip_atomic_fetch_add(ctr, 1u, __ATOMIC_ACQ_REL, __HIP_MEMORY_SCOPE_AGENT);
    unsigned cnt;
    do {
        cnt = __hip_atomic_load(ctr, __ATOMIC_ACQUIRE, __HIP_MEMORY_SCOPE_AGENT);
        if (cnt < NBLK) __builtin_amdgcn_s_sleep(2);
    } while (cnt < NBLK);
    __builtin_amdgcn_fence(__ATOMIC_ACQUIRE, "agent");   // invalidate caches

    // ---------------- fused epilogue + batch mean ----------------
    // E_b(i,j) = exp2( K2*theta + F'tot_b - F'_b(i,j) - B'_b(i,j) );
    // block blk owns output rows 2*blk, 2*blk+1; thread t: row 2*blk+(t>>5),
    // cols 4*(t&31) and 4*(t&31)+128.
    {
        const int t = threadIdx.x;
        const int row = 2 * blk + (t >> 5);
        const int cb  = 4 * (t & 31);
        const size_t off0 = (size_t)row * NN + cb;
        const size_t off1 = off0 + 128;
        float4 acc0 = make_float4(0.f, 0.f, 0.f, 0.f);
        float4 acc1 = make_float4(0.f, 0.f, 0.f, 0.f);
        for (int p = 0; p < NB; ++p) {
            const float* __restrict__ thp = D + (size_t)p * (MM * NN);
            const float* __restrict__ fp  = ws + (size_t)p * (MM * NN);
            const float* __restrict__ bp  = ws + (size_t)(NB + p) * (MM * NN);
            const float Ft = fp[MM * NN - 1];                 // F'tot = F'(M,N)
            const float4 t0 = *(const float4*)(thp + off0);
            const float4 f0 = *(const float4*)(fp + off0);
            const float4 b0 = *(const float4*)(bp + off0);
            acc0.x += exp2f(fmaf(t0.x, K2, (Ft - f0.x) - b0.x));
            acc0.y += exp2f(fmaf(t0.y, K2, (Ft - f0.y) - b0.y));
            acc0.z += exp2f(fmaf(t0.z, K2, (Ft - f0.z) - b0.z));
            acc0.w += exp2f(fmaf(t0.w, K2, (Ft - f0.w) - b0.w));
            const float4 t1 = *(const float4*)(thp + off1);
            const float4 f1 = *(const float4*)(fp + off1);
            const float4 b1 = *(const float4*)(bp + off1);
            acc1.x += exp2f(fmaf(t1.x, K2, (Ft - f1.x) - b1.x));
            acc1.y += exp2f(fmaf(t1.y, K2, (Ft - f1.y) - b1.y));
            acc1.z += exp2f(fmaf(t1.z, K2, (Ft - f1.z) - b1.z));
            acc1.w += exp2f(fmaf(t1.w, K2, (Ft - f1.w) - b1.w));
        }
        const float inv = 1.0f / (float)NB;
        *(float4*)(out + off0) =
            make_float4(acc0.x * inv, acc0.y * inv, acc0.z * inv, acc0.w * inv);
        *(float4*)(out + off1) =
            make_float4(acc1.x * inv, acc1.y * inv, acc1.z * inv, acc1.w * inv);
    }
}

extern "C" void kernel_launch(void* const* d_in, const int* in_sizes, int n_in,
                              void* d_out, int out_size, void* d_ws, size_t ws_size,
                              hipStream_t stream) {
    const float* D = (const float*)d_in[0];
    float* out = (float*)d_out;
    float* ws = (float*)d_ws;

    // zero the barrier counter (ws is re-poisoned 0xAA before every launch)
    hipMemsetAsync(ws + (size_t)2 * NB * (MM * NN), 0, sizeof(unsigned), stream);
    dtw_fb<<<dim3(NBLK), dim3(64), 0, stream>>>(D, out, ws);
}